// Round 4
// baseline (159.369 us; speedup 1.0000x reference)
//
#include <hip/hip_runtime.h>

#define NN  50000
#define DEG 32
#define DF  128
#define DO  256
#define FEAT4 (NN * DF / 4)   // 1,600,000 float4 groups

typedef __bf16 bf16x8 __attribute__((ext_vector_type(8)));
typedef float  f32x4  __attribute__((ext_vector_type(4)));
typedef float  f32x2  __attribute__((ext_vector_type(2)));
typedef unsigned short u16x8 __attribute__((ext_vector_type(8)));

#if defined(__has_builtin)
#if __has_builtin(__builtin_amdgcn_cvt_pk_f32_fp8) && __has_builtin(__builtin_amdgcn_cvt_pk_fp8_f32)
#define HW_FP8 1
#endif
#endif
#ifndef HW_FP8
#define HW_FP8 0
#endif

__device__ __forceinline__ unsigned short f2bf(float f) {
    unsigned u = __float_as_uint(f);
    u += 0x7FFF + ((u >> 16) & 1);     // round-to-nearest-even
    return (unsigned short)(u >> 16);
}

#if !HW_FP8
__device__ __forceinline__ unsigned enc1_fp8(float f) {
    unsigned u = __float_as_uint(f);
    unsigned s = (u >> 31) << 7;
    float a = fabsf(f);
    if (!(a > 0.f)) return s;
    if (a >= 448.f) return s | 0x7E;
    u = __float_as_uint(a);
    int e = (int)((u >> 23) & 255) - 127;
    if (e < -6) {
        unsigned m = (unsigned)(a * 512.f + 0.5f);
        if (m >= 8) return s | 0x08;
        return s | m;
    }
    unsigned mant = (u >> 20) & 7;
    unsigned rnd  = ((u >> 19) & 1) & (((u & 0x7FFFF) != 0) | ((u >> 20) & 1));
    unsigned enc  = ((unsigned)(e + 7) << 3) | mant;
    return s | (enc + rnd);
}
__device__ __forceinline__ float dec1_fp8(unsigned b) {
    unsigned s = (b >> 7) & 1, e = (b >> 3) & 15, m = b & 7;
    float v = (e == 0) ? (float)m * 0.001953125f
                       : __uint_as_float(((e - 7 + 127) << 23) | (m << 20));
    return s ? -v : v;
}
#endif

__device__ __forceinline__ unsigned enc4_fp8(float4 v) {
#if HW_FP8
    int pk = 0;
    pk = __builtin_amdgcn_cvt_pk_fp8_f32(v.x, v.y, pk, false);
    pk = __builtin_amdgcn_cvt_pk_fp8_f32(v.z, v.w, pk, true);
    return (unsigned)pk;
#else
    return enc1_fp8(v.x) | (enc1_fp8(v.y) << 8) | (enc1_fp8(v.z) << 16) | (enc1_fp8(v.w) << 24);
#endif
}

// ---------------------------------------------------------------------------
// Convert: feat fp32 -> fp8 e4m3 gather table;  W fp32 [K][N] -> Wt bf16 [N][K].
// ---------------------------------------------------------------------------
__global__ __launch_bounds__(256) void convert_kernel(
    const float* __restrict__ feat, const float* __restrict__ W,
    unsigned* __restrict__ feat8, unsigned short* __restrict__ Wt)
{
    const int gid = blockIdx.x * 256 + threadIdx.x;
    if (gid < FEAT4) {
        const float4 v = ((const float4*)feat)[gid];
        feat8[gid] = enc4_fp8(v);
    } else {
        const int t = gid - FEAT4;
        if (t < DO * DO) {
            const int n = t >> 8, k = t & 255;
            Wt[n * DO + k] = f2bf(W[k * DO + n]);   // write coalesced along k
        }
    }
}

// ---------------------------------------------------------------------------
// Fused aggregation + GEMM, v4: cross-block overlap, single barrier.
//  BM=32, BN=256, 512 threads (8 waves 2m x 4n), grid=1563 (~6 generations
//  of backfill at 4 blocks/CU -> gathering blocks overlap MFMA blocks).
//  - A staged ONCE into LDS [32][264]: cols 0..127 self (fp32->bf16),
//    cols 128..255 agg (from gather regs). ONE __syncthreads total.
//  - B read directly from L2-resident Wt (128 KB): no B staging, no per-kc
//    barriers, loads hoisted freely by the compiler and hidden by 32 waves.
//  - LDA=264: fragment-read bank stride 132 dwords -> 2-way (free).
//  - __launch_bounds__(512,8) pins VGPR<=64 -> 4 blocks/CU (32-wave cap).
// ---------------------------------------------------------------------------
#define BM  32
#define LDA 264

__global__ __launch_bounds__(512, 8) void fused_kernel(
    const float*          __restrict__ feat,
    const unsigned*       __restrict__ feat8,
    const int*            __restrict__ edges,
    const unsigned short* __restrict__ Wt,
    float*                __restrict__ out)
{
    __shared__ __align__(16) unsigned short Asw[BM * LDA];   // 16.9 KB

    const int tid = threadIdx.x;
    const int m0  = blockIdx.x * BM;
    const int rn  = tid >> 4;          // row 0..31 (node within block)
    const int l   = tid & 15;          // lane owns feature cols [8l, 8l+8)

    int gnode = m0 + rn;
    if (gnode >= NN) gnode = NN - 1;

    // ---- A-self: 32 rows x 128 cols, fp32 -> bf16, one u16x8 per thread
    {
        const float* src = feat + (size_t)gnode * DF + l * 8;
        const float4 v0 = *(const float4*)(src);
        const float4 v1 = *(const float4*)(src + 4);
        u16x8 o;
        o[0] = f2bf(v0.x); o[1] = f2bf(v0.y); o[2] = f2bf(v0.z); o[3] = f2bf(v0.w);
        o[4] = f2bf(v1.x); o[5] = f2bf(v1.y); o[6] = f2bf(v1.z); o[7] = f2bf(v1.w);
        *(u16x8*)(Asw + rn * LDA + l * 8) = o;
    }

    // ---- gather + mean (one pass, loop-carried loads; 32 waves/CU hide it)
    {
        const int* e = edges + (size_t)gnode * DEG;
        float a[8] = {0.f, 0.f, 0.f, 0.f, 0.f, 0.f, 0.f, 0.f};
        #pragma unroll
        for (int d = 0; d < DEG; ++d) {
            const int idx = e[d];
            const uint2 pk = *(const uint2*)(feat8 + (size_t)idx * (DF / 4) + l * 2);
#if HW_FP8
            const f32x2 v0 = __builtin_amdgcn_cvt_pk_f32_fp8((int)pk.x, false);
            const f32x2 v1 = __builtin_amdgcn_cvt_pk_f32_fp8((int)pk.x, true);
            const f32x2 v2 = __builtin_amdgcn_cvt_pk_f32_fp8((int)pk.y, false);
            const f32x2 v3 = __builtin_amdgcn_cvt_pk_f32_fp8((int)pk.y, true);
            a[0] += v0[0]; a[1] += v0[1]; a[2] += v1[0]; a[3] += v1[1];
            a[4] += v2[0]; a[5] += v2[1]; a[6] += v3[0]; a[7] += v3[1];
#else
            #pragma unroll
            for (int j = 0; j < 4; ++j) a[j]     += dec1_fp8((pk.x >> (8 * j)) & 255);
            #pragma unroll
            for (int j = 0; j < 4; ++j) a[4 + j] += dec1_fp8((pk.y >> (8 * j)) & 255);
#endif
        }
        const float s = 1.0f / (float)DEG;
        u16x8 aggr;
        #pragma unroll
        for (int j = 0; j < 8; ++j) aggr[j] = f2bf(a[j] * s);
        *(u16x8*)(Asw + rn * LDA + 128 + l * 8) = aggr;
    }

    __syncthreads();   // the ONLY barrier: full A tile (self+agg) ready

    // ---- GEMM: 8 waves = 2m x 4n; wave tile 16 x 64; B direct from Wt (L2)
    const int wave = tid >> 6, lane = tid & 63;
    const int quad = lane >> 4, lr = lane & 15;
    const int wm   = (wave & 1) * 16;
    const int wn   = (wave >> 1) * 64;

    f32x4 acc[4] = {};

    #pragma unroll
    for (int kc = 0; kc < 4; ++kc) {
        #pragma unroll
        for (int kk = 0; kk < 64; kk += 32) {
            const int kb = kc * 64 + kk + quad * 8;
            const bf16x8 af = *(const bf16x8*)(Asw + (wm + lr) * LDA + kb);
            #pragma unroll
            for (int ni = 0; ni < 4; ++ni) {
                const bf16x8 bfr =
                    *(const bf16x8*)(Wt + (size_t)(wn + ni * 16 + lr) * DO + kb);
                acc[ni] = __builtin_amdgcn_mfma_f32_16x16x32_bf16(
                    af, bfr, acc[ni], 0, 0, 0);
            }
        }
    }

    // ---- epilogue: relu + store
    #pragma unroll
    for (int r = 0; r < 4; ++r) {
        const int row = m0 + wm + quad * 4 + r;
        if (row < NN) {
            #pragma unroll
            for (int ni = 0; ni < 4; ++ni) {
                out[(size_t)row * DO + wn + ni * 16 + lr] =
                    fmaxf(acc[ni][r], 0.f);
            }
        }
    }
}

extern "C" void kernel_launch(void* const* d_in, const int* in_sizes, int n_in,
                              void* d_out, int out_size, void* d_ws, size_t ws_size,
                              hipStream_t stream)
{
    const float* feat  = (const float*)d_in[0];
    const int*   edges = (const int*)d_in[1];
    const float* W     = (const float*)d_in[2];
    float*       out   = (float*)d_out;

    unsigned*       feat8 = (unsigned*)d_ws;                          // 6.4 MB
    unsigned short* Wt    = (unsigned short*)(feat8 + (size_t)NN * DF / 4); // 128 KB

    convert_kernel<<<(FEAT4 + DO * DO + 255) / 256, 256, 0, stream>>>(
        feat, W, feat8, Wt);

    fused_kernel<<<(NN + BM - 1) / BM, 512, 0, stream>>>(
        feat, feat8, edges, Wt, out);
}

// Round 5
// 146.923 us; speedup vs baseline: 1.0847x; 1.0847x over previous
//
#include <hip/hip_runtime.h>

#define NN  50000
#define DEG 32
#define DF  128
#define DO  256
#define FEAT4 (NN * DF / 4)   // 1,600,000 float4 groups

typedef __bf16 bf16x8 __attribute__((ext_vector_type(8)));
typedef float  f32x4  __attribute__((ext_vector_type(4)));
typedef float  f32x2  __attribute__((ext_vector_type(2)));
typedef unsigned short u16x8 __attribute__((ext_vector_type(8)));

#if defined(__has_builtin)
#if __has_builtin(__builtin_amdgcn_cvt_pk_f32_fp8) && __has_builtin(__builtin_amdgcn_cvt_pk_fp8_f32)
#define HW_FP8 1
#endif
#endif
#ifndef HW_FP8
#define HW_FP8 0
#endif

__device__ __forceinline__ unsigned short f2bf(float f) {
    unsigned u = __float_as_uint(f);
    u += 0x7FFF + ((u >> 16) & 1);     // round-to-nearest-even
    return (unsigned short)(u >> 16);
}

#if !HW_FP8
__device__ __forceinline__ unsigned enc1_fp8(float f) {
    unsigned u = __float_as_uint(f);
    unsigned s = (u >> 31) << 7;
    float a = fabsf(f);
    if (!(a > 0.f)) return s;
    if (a >= 448.f) return s | 0x7E;
    u = __float_as_uint(a);
    int e = (int)((u >> 23) & 255) - 127;
    if (e < -6) {
        unsigned m = (unsigned)(a * 512.f + 0.5f);
        if (m >= 8) return s | 0x08;
        return s | m;
    }
    unsigned mant = (u >> 20) & 7;
    unsigned rnd  = ((u >> 19) & 1) & (((u & 0x7FFFF) != 0) | ((u >> 20) & 1));
    unsigned enc  = ((unsigned)(e + 7) << 3) | mant;
    return s | (enc + rnd);
}
__device__ __forceinline__ float dec1_fp8(unsigned b) {
    unsigned s = (b >> 7) & 1, e = (b >> 3) & 15, m = b & 7;
    float v = (e == 0) ? (float)m * 0.001953125f
                       : __uint_as_float(((e - 7 + 127) << 23) | (m << 20));
    return s ? -v : v;
}
#endif

__device__ __forceinline__ unsigned enc4_fp8(float4 v) {
#if HW_FP8
    int pk = 0;
    pk = __builtin_amdgcn_cvt_pk_fp8_f32(v.x, v.y, pk, false);
    pk = __builtin_amdgcn_cvt_pk_fp8_f32(v.z, v.w, pk, true);
    return (unsigned)pk;
#else
    return enc1_fp8(v.x) | (enc1_fp8(v.y) << 8) | (enc1_fp8(v.z) << 16) | (enc1_fp8(v.w) << 24);
#endif
}

// ---------------------------------------------------------------------------
// Convert: feat fp32 -> fp8 e4m3 gather table;  W fp32 [K][N] -> Wt bf16 [N][K].
// ---------------------------------------------------------------------------
__global__ __launch_bounds__(256) void convert_kernel(
    const float* __restrict__ feat, const float* __restrict__ W,
    unsigned* __restrict__ feat8, unsigned short* __restrict__ Wt)
{
    const int gid = blockIdx.x * 256 + threadIdx.x;
    if (gid < FEAT4) {
        const float4 v = ((const float4*)feat)[gid];
        feat8[gid] = enc4_fp8(v);
    } else {
        const int t = gid - FEAT4;
        if (t < DO * DO) {
            const int n = t >> 8, k = t & 255;
            Wt[n * DO + k] = f2bf(W[k * DO + n]);   // write coalesced along k
        }
    }
}

// ---------------------------------------------------------------------------
// Fused aggregation + GEMM, v5: R2's proven skeleton, halved M for backfill.
//  BM=32, BN=256, 512 threads (8 waves 2m x 4n), grid=1563.
//  - 1-pass gather: 1 node per 16-lane group (800K threads = identical TLP
//    to the standalone 18 us agg kernel). No launch-bounds forcing, no
//    issue-early games: compiler schedules the unrolled 32-load loop.
//  - GEMM body = R2 verbatim (LDS-staged A and B per kc, LDT=72, per-kc
//    barriers, 16x16x32 MFMA): the twice-proven structure.
//  - LDS 41.5 KB -> 3 blocks/CU -> 2.03 grid generations: second-generation
//    gathers overlap first-generation GEMMs (cross-block latency hiding).
// ---------------------------------------------------------------------------
#define BM  32
#define BN  256
#define LDT 72

__global__ __launch_bounds__(512) void fused_kernel(
    const float*          __restrict__ feat,
    const unsigned*       __restrict__ feat8,
    const int*            __restrict__ edges,
    const unsigned short* __restrict__ Wt,
    float*                __restrict__ out)
{
    __shared__ __align__(16) unsigned short Asw[BM * LDT];   //  4.6 KB
    __shared__ __align__(16) unsigned short Bsw[BN * LDT];   // 36.9 KB

    const int tid = threadIdx.x;
    const int m0  = blockIdx.x * BM;
    const int rn  = tid >> 4;          // node row 0..31
    const int l   = tid & 15;          // lane owns feature cols [8l, 8l+8)

    int gnode = m0 + rn;
    if (gnode >= NN) gnode = NN - 1;

    // ---- 1-pass gather + mean -> aggr regs (feeds kc=2,3)
    u16x8 aggr;
    {
        const int* e = edges + (size_t)gnode * DEG;
        float a[8] = {0.f, 0.f, 0.f, 0.f, 0.f, 0.f, 0.f, 0.f};
        #pragma unroll
        for (int d = 0; d < DEG; ++d) {
            const int idx = e[d];
            const uint2 pk = *(const uint2*)(feat8 + (size_t)idx * (DF / 4) + l * 2);
#if HW_FP8
            const f32x2 v0 = __builtin_amdgcn_cvt_pk_f32_fp8((int)pk.x, false);
            const f32x2 v1 = __builtin_amdgcn_cvt_pk_f32_fp8((int)pk.x, true);
            const f32x2 v2 = __builtin_amdgcn_cvt_pk_f32_fp8((int)pk.y, false);
            const f32x2 v3 = __builtin_amdgcn_cvt_pk_f32_fp8((int)pk.y, true);
            a[0] += v0[0]; a[1] += v0[1]; a[2] += v1[0]; a[3] += v1[1];
            a[4] += v2[0]; a[5] += v2[1]; a[6] += v3[0]; a[7] += v3[1];
#else
            #pragma unroll
            for (int j = 0; j < 4; ++j) a[j]     += dec1_fp8((pk.x >> (8 * j)) & 255);
            #pragma unroll
            for (int j = 0; j < 4; ++j) a[4 + j] += dec1_fp8((pk.y >> (8 * j)) & 255);
#endif
        }
        const float s = 1.0f / (float)DEG;
        #pragma unroll
        for (int j = 0; j < 8; ++j) aggr[j] = f2bf(a[j] * s);
    }

    // ---- GEMM: 8 waves = 2m x 4n; wave tile 16 x 64
    const int wave = tid >> 6, lane = tid & 63;
    const int quad = lane >> 4, lr = lane & 15;
    const int wm   = (wave & 1) * 16;
    const int wn   = (wave >> 1) * 64;

    f32x4 acc[4] = {};

    for (int kc = 0; kc < 4; ++kc) {
        if (kc) __syncthreads();       // protect previous iteration's reads

        if (kc < 2) {
            // A chunk from fp32 self features: 32 rows x 64 cols (threads 0-255)
            if (tid < 256) {
                const int r = tid >> 3;
                const int c = (tid & 7) * 8;
                int node = m0 + r;
                if (node >= NN) node = NN - 1;
                const float* src = feat + (size_t)node * DF + kc * 64 + c;
                const float4 v0 = *(const float4*)(src);
                const float4 v1 = *(const float4*)(src + 4);
                u16x8 o;
                o[0] = f2bf(v0.x); o[1] = f2bf(v0.y); o[2] = f2bf(v0.z); o[3] = f2bf(v0.w);
                o[4] = f2bf(v1.x); o[5] = f2bf(v1.y); o[6] = f2bf(v1.z); o[7] = f2bf(v1.w);
                *(u16x8*)(Asw + r * LDT + c) = o;
            }
        } else if ((l >> 3) == (kc - 2)) {
            // A chunk from agg registers (kc=2: lanes l<8 -> cols 0..63;
            //                             kc=3: lanes l>=8 -> cols 64..127)
            const int c = (l & 7) * 8;
            *(u16x8*)(Asw + rn * LDT + c) = aggr;
        }

        // B chunk: 256 rows x 64 cols from Wt (L2-resident), 4 segs/thread
        #pragma unroll
        for (int it = 0; it < 4; ++it) {
            const int sidx = it * 512 + tid;
            const int r = sidx >> 3;
            const int c = (sidx & 7) * 8;
            *(u16x8*)(Bsw + r * LDT + c) =
                *(const u16x8*)(Wt + (size_t)r * DO + kc * 64 + c);
        }

        __syncthreads();

        #pragma unroll
        for (int kk = 0; kk < 64; kk += 32) {
            const int kb = kk + quad * 8;
            const bf16x8 af = *(const bf16x8*)(Asw + (wm + lr) * LDT + kb);
            bf16x8 bfr[4];
            #pragma unroll
            for (int i = 0; i < 4; ++i)
                bfr[i] = *(const bf16x8*)(Bsw + (wn + i * 16 + lr) * LDT + kb);
            #pragma unroll
            for (int ni = 0; ni < 4; ++ni)
                acc[ni] = __builtin_amdgcn_mfma_f32_16x16x32_bf16(
                    af, bfr[ni], acc[ni], 0, 0, 0);
        }
    }

    // ---- epilogue: relu + store
    #pragma unroll
    for (int r = 0; r < 4; ++r) {
        const int row = m0 + wm + quad * 4 + r;
        if (row < NN) {
            #pragma unroll
            for (int ni = 0; ni < 4; ++ni) {
                out[(size_t)row * DO + wn + ni * 16 + lr] =
                    fmaxf(acc[ni][r], 0.f);
            }
        }
    }
}

extern "C" void kernel_launch(void* const* d_in, const int* in_sizes, int n_in,
                              void* d_out, int out_size, void* d_ws, size_t ws_size,
                              hipStream_t stream)
{
    const float* feat  = (const float*)d_in[0];
    const int*   edges = (const int*)d_in[1];
    const float* W     = (const float*)d_in[2];
    float*       out   = (float*)d_out;

    unsigned*       feat8 = (unsigned*)d_ws;                          // 6.4 MB
    unsigned short* Wt    = (unsigned short*)(feat8 + (size_t)NN * DF / 4); // 128 KB

    convert_kernel<<<(FEAT4 + DO * DO + 255) / 256, 256, 0, stream>>>(
        feat, W, feat8, Wt);

    fused_kernel<<<(NN + BM - 1) / BM, 512, 0, stream>>>(
        feat, feat8, edges, Wt, out);
}

// Round 6
// 124.587 us; speedup vs baseline: 1.2792x; 1.1793x over previous
//
#include <hip/hip_runtime.h>

#define NN  50000
#define DEG 32
#define DF  128
#define DO  256
#define FEAT4 (NN * DF / 4)   // 1,600,000 float4 groups

typedef __bf16 bf16x8 __attribute__((ext_vector_type(8)));
typedef float  f32x4  __attribute__((ext_vector_type(4)));
typedef float  f32x2  __attribute__((ext_vector_type(2)));
typedef unsigned short u16x8 __attribute__((ext_vector_type(8)));

#if defined(__has_builtin)
#if __has_builtin(__builtin_amdgcn_cvt_pk_f32_fp8) && __has_builtin(__builtin_amdgcn_cvt_pk_fp8_f32)
#define HW_FP8 1
#endif
#endif
#ifndef HW_FP8
#define HW_FP8 0
#endif

__device__ __forceinline__ unsigned short f2bf(float f) {
    unsigned u = __float_as_uint(f);
    u += 0x7FFF + ((u >> 16) & 1);     // round-to-nearest-even
    return (unsigned short)(u >> 16);
}

#if !HW_FP8
__device__ __forceinline__ unsigned enc1_fp8(float f) {
    unsigned u = __float_as_uint(f);
    unsigned s = (u >> 31) << 7;
    float a = fabsf(f);
    if (!(a > 0.f)) return s;
    if (a >= 448.f) return s | 0x7E;
    u = __float_as_uint(a);
    int e = (int)((u >> 23) & 255) - 127;
    if (e < -6) {
        unsigned m = (unsigned)(a * 512.f + 0.5f);
        if (m >= 8) return s | 0x08;
        return s | m;
    }
    unsigned mant = (u >> 20) & 7;
    unsigned rnd  = ((u >> 19) & 1) & (((u & 0x7FFFF) != 0) | ((u >> 20) & 1));
    unsigned enc  = ((unsigned)(e + 7) << 3) | mant;
    return s | (enc + rnd);
}
__device__ __forceinline__ float dec1_fp8(unsigned b) {
    unsigned s = (b >> 7) & 1, e = (b >> 3) & 15, m = b & 7;
    float v = (e == 0) ? (float)m * 0.001953125f
                       : __uint_as_float(((e - 7 + 127) << 23) | (m << 20));
    return s ? -v : v;
}
#endif

__device__ __forceinline__ unsigned enc4_fp8(float4 v) {
#if HW_FP8
    int pk = 0;
    pk = __builtin_amdgcn_cvt_pk_fp8_f32(v.x, v.y, pk, false);
    pk = __builtin_amdgcn_cvt_pk_fp8_f32(v.z, v.w, pk, true);
    return (unsigned)pk;
#else
    return enc1_fp8(v.x) | (enc1_fp8(v.y) << 8) | (enc1_fp8(v.z) << 16) | (enc1_fp8(v.w) << 24);
#endif
}

// ---------------------------------------------------------------------------
// Convert (R0 verbatim): feat fp32 -> {fp8 e4m3 gather table, bf16 GEMM copy};
//          W fp32 [K][N] -> Wt bf16 [N][K].
// ---------------------------------------------------------------------------
__global__ __launch_bounds__(256) void convert_kernel(
    const float* __restrict__ feat, const float* __restrict__ W,
    unsigned* __restrict__ feat8, unsigned short* __restrict__ featb,
    unsigned short* __restrict__ Wt)
{
    const int gid = blockIdx.x * 256 + threadIdx.x;
    if (gid < FEAT4) {
        const float4 v = ((const float4*)feat)[gid];
        feat8[gid] = enc4_fp8(v);
        ushort4 o;
        o.x = f2bf(v.x); o.y = f2bf(v.y); o.z = f2bf(v.z); o.w = f2bf(v.w);
        ((ushort4*)featb)[gid] = o;
    } else {
        const int t = gid - FEAT4;
        if (t < DO * DO) {
            const int n = t >> 8, k = t & 255;
            Wt[n * DO + k] = f2bf(W[k * DO + n]);   // write coalesced along k
        }
    }
}

// ---------------------------------------------------------------------------
// Aggregation (R0 verbatim): proven ~18 us. 16 nodes/block, 16 lanes/node x
// 8 B, fp32 accumulate, bf16 out. High TLP (800K threads, 8 blocks/CU).
// ---------------------------------------------------------------------------
__global__ __launch_bounds__(256) void agg_kernel(
    const unsigned* __restrict__ feat8,
    const int*      __restrict__ edges,
    unsigned short* __restrict__ aggb)
{
    const int node = blockIdx.x * 16 + (threadIdx.x >> 4);
    const int l    = threadIdx.x & 15;
    const int* e   = edges + node * DEG;

    float a[8] = {0.f, 0.f, 0.f, 0.f, 0.f, 0.f, 0.f, 0.f};
    #pragma unroll
    for (int d = 0; d < DEG; ++d) {
        const int idx = e[d];
        const uint2 pk = *(const uint2*)(feat8 + (size_t)idx * (DF / 4) + l * 2);
#if HW_FP8
        const f32x2 v0 = __builtin_amdgcn_cvt_pk_f32_fp8((int)pk.x, false);
        const f32x2 v1 = __builtin_amdgcn_cvt_pk_f32_fp8((int)pk.x, true);
        const f32x2 v2 = __builtin_amdgcn_cvt_pk_f32_fp8((int)pk.y, false);
        const f32x2 v3 = __builtin_amdgcn_cvt_pk_f32_fp8((int)pk.y, true);
        a[0] += v0[0]; a[1] += v0[1]; a[2] += v1[0]; a[3] += v1[1];
        a[4] += v2[0]; a[5] += v2[1]; a[6] += v3[0]; a[7] += v3[1];
#else
        #pragma unroll
        for (int j = 0; j < 4; ++j) a[j]     += dec1_fp8((pk.x >> (8 * j)) & 255);
        #pragma unroll
        for (int j = 0; j < 4; ++j) a[4 + j] += dec1_fp8((pk.y >> (8 * j)) & 255);
#endif
    }

    const float s = 1.0f / (float)DEG;
    u16x8 o;
    #pragma unroll
    for (int j = 0; j < 8; ++j) o[j] = f2bf(a[j] * s);
    *(u16x8*)(aggb + (size_t)node * DF + l * 8) = o;
}

// ---------------------------------------------------------------------------
// GEMM v6: R2's proven fused-GEMM body, standalone. BM=64, BN=256 (full DO,
// A read ONCE), 512 threads = 8 waves 2m x 4n (wave tile 32x64), K in 4
// chunks of 64 staged through LDS (LDT=72: 2-way conflicts, free), 16x16x32
// bf16 MFMA, acc 2x4. LDS 45 KB -> 3 blocks/CU; ~60 VGPR -> not reg-capped.
// ---------------------------------------------------------------------------
#define BM  64
#define BN  256
#define LDT 72

__global__ __launch_bounds__(512) void gemm_kernel(
    const unsigned short* __restrict__ featb,
    const unsigned short* __restrict__ aggb,
    const unsigned short* __restrict__ Wt,
    float*                __restrict__ out)
{
    __shared__ __align__(16) unsigned short Asw[BM * LDT];   //  9.2 KB
    __shared__ __align__(16) unsigned short Bsw[BN * LDT];   // 36.9 KB

    const int tid = threadIdx.x;
    const int m0  = blockIdx.x * BM;

    const int wave = tid >> 6, lane = tid & 63;
    const int quad = lane >> 4, lr = lane & 15;
    const int wm   = (wave & 1) * 32;
    const int wn   = (wave >> 1) * 64;

    f32x4 acc[2][4] = {};

    for (int kc = 0; kc < 4; ++kc) {
        const unsigned short* srcA = (kc < 2) ? (featb + kc * 64)
                                              : (aggb + (kc - 2) * 64);

        if (kc) __syncthreads();

        // A chunk: 64 rows x 64 cols, 1 seg/thread (bf16 source, 16B loads)
        {
            const int r = tid >> 3;
            const int c = (tid & 7) * 8;
            int node = m0 + r;
            if (node >= NN) node = NN - 1;
            *(u16x8*)(Asw + r * LDT + c) =
                *(const u16x8*)(srcA + (size_t)node * DF + c);
        }

        // B chunk: 256 rows x 64 cols from Wt (L2-resident), 4 segs/thread
        #pragma unroll
        for (int it = 0; it < 4; ++it) {
            const int sidx = it * 512 + tid;
            const int r = sidx >> 3;
            const int c = (sidx & 7) * 8;
            *(u16x8*)(Bsw + r * LDT + c) =
                *(const u16x8*)(Wt + (size_t)r * DO + kc * 64 + c);
        }

        __syncthreads();

        #pragma unroll
        for (int kk = 0; kk < 64; kk += 32) {
            const int kb = kk + quad * 8;
            bf16x8 af[2], bfr[4];
            #pragma unroll
            for (int i = 0; i < 2; ++i)
                af[i] = *(const bf16x8*)(Asw + (wm + i * 16 + lr) * LDT + kb);
            #pragma unroll
            for (int i = 0; i < 4; ++i)
                bfr[i] = *(const bf16x8*)(Bsw + (wn + i * 16 + lr) * LDT + kb);
            #pragma unroll
            for (int mi = 0; mi < 2; ++mi)
                #pragma unroll
                for (int ni = 0; ni < 4; ++ni)
                    acc[mi][ni] = __builtin_amdgcn_mfma_f32_16x16x32_bf16(
                        af[mi], bfr[ni], acc[mi][ni], 0, 0, 0);
        }
    }

    // ---- epilogue: relu + store
    #pragma unroll
    for (int mi = 0; mi < 2; ++mi) {
        #pragma unroll
        for (int r = 0; r < 4; ++r) {
            const int row = m0 + wm + mi * 16 + quad * 4 + r;
            if (row < NN) {
                #pragma unroll
                for (int ni = 0; ni < 4; ++ni) {
                    out[(size_t)row * DO + wn + ni * 16 + lr] =
                        fmaxf(acc[mi][ni][r], 0.f);
                }
            }
        }
    }
}

extern "C" void kernel_launch(void* const* d_in, const int* in_sizes, int n_in,
                              void* d_out, int out_size, void* d_ws, size_t ws_size,
                              hipStream_t stream)
{
    const float* feat  = (const float*)d_in[0];
    const int*   edges = (const int*)d_in[1];
    const float* W     = (const float*)d_in[2];
    float*       out   = (float*)d_out;

    unsigned short* aggb  = (unsigned short*)d_ws;                 // 12.8 MB
    unsigned*       feat8 = (unsigned*)(aggb + (size_t)NN * DF);   // 6.4 MB
    unsigned short* featb = (unsigned short*)(feat8 + (size_t)NN * DF / 4); // 12.8 MB
    unsigned short* Wt    = featb + (size_t)NN * DF;               // 128 KB

    convert_kernel<<<(FEAT4 + DO * DO + 255) / 256, 256, 0, stream>>>(
        feat, W, feat8, featb, Wt);
    agg_kernel<<<NN / 16, 256, 0, stream>>>(feat8, edges, aggb);

    gemm_kernel<<<(NN + BM - 1) / BM, 512, 0, stream>>>(featb, aggb, Wt, out);
}

// Round 7
// 124.062 us; speedup vs baseline: 1.2846x; 1.0042x over previous
//
#include <hip/hip_runtime.h>

#define NN  50000
#define DEG 32
#define DF  128
#define DO  256
#define FEAT4 (NN * DF / 4)   // 1,600,000 float4 groups

typedef __bf16 bf16x8 __attribute__((ext_vector_type(8)));
typedef float  f32x4  __attribute__((ext_vector_type(4)));
typedef float  f32x2  __attribute__((ext_vector_type(2)));
typedef unsigned short u16x8 __attribute__((ext_vector_type(8)));

#if defined(__has_builtin)
#if __has_builtin(__builtin_amdgcn_cvt_pk_f32_fp8) && __has_builtin(__builtin_amdgcn_cvt_pk_fp8_f32)
#define HW_FP8 1
#endif
#endif
#ifndef HW_FP8
#define HW_FP8 0
#endif

__device__ __forceinline__ unsigned short f2bf(float f) {
    unsigned u = __float_as_uint(f);
    u += 0x7FFF + ((u >> 16) & 1);     // round-to-nearest-even
    return (unsigned short)(u >> 16);
}

#if !HW_FP8
__device__ __forceinline__ unsigned enc1_fp8(float f) {
    unsigned u = __float_as_uint(f);
    unsigned s = (u >> 31) << 7;
    float a = fabsf(f);
    if (!(a > 0.f)) return s;
    if (a >= 448.f) return s | 0x7E;
    u = __float_as_uint(a);
    int e = (int)((u >> 23) & 255) - 127;
    if (e < -6) {
        unsigned m = (unsigned)(a * 512.f + 0.5f);
        if (m >= 8) return s | 0x08;
        return s | m;
    }
    unsigned mant = (u >> 20) & 7;
    unsigned rnd  = ((u >> 19) & 1) & (((u & 0x7FFFF) != 0) | ((u >> 20) & 1));
    unsigned enc  = ((unsigned)(e + 7) << 3) | mant;
    return s | (enc + rnd);
}
__device__ __forceinline__ float dec1_fp8(unsigned b) {
    unsigned s = (b >> 7) & 1, e = (b >> 3) & 15, m = b & 7;
    float v = (e == 0) ? (float)m * 0.001953125f
                       : __uint_as_float(((e - 7 + 127) << 23) | (m << 20));
    return s ? -v : v;
}
#endif

__device__ __forceinline__ unsigned enc4_fp8(float4 v) {
#if HW_FP8
    int pk = 0;
    pk = __builtin_amdgcn_cvt_pk_fp8_f32(v.x, v.y, pk, false);
    pk = __builtin_amdgcn_cvt_pk_fp8_f32(v.z, v.w, pk, true);
    return (unsigned)pk;
#else
    return enc1_fp8(v.x) | (enc1_fp8(v.y) << 8) | (enc1_fp8(v.z) << 16) | (enc1_fp8(v.w) << 24);
#endif
}

// ---------------------------------------------------------------------------
// Convert: feat fp32 -> fp8 e4m3 gather table; W fp32 [K][N] -> Wt bf16 [N][K].
// (featb dropped: gemm converts A-self inline from fp32 — identical f2bf.)
// ---------------------------------------------------------------------------
__global__ __launch_bounds__(256) void convert_kernel(
    const float* __restrict__ feat, const float* __restrict__ W,
    unsigned* __restrict__ feat8, unsigned short* __restrict__ Wt)
{
    const int gid = blockIdx.x * 256 + threadIdx.x;
    if (gid < FEAT4) {
        const float4 v = ((const float4*)feat)[gid];
        feat8[gid] = enc4_fp8(v);
    } else {
        const int t = gid - FEAT4;
        if (t < DO * DO) {
            const int n = t >> 8, k = t & 255;
            Wt[n * DO + k] = f2bf(W[k * DO + n]);   // write coalesced along k
        }
    }
}

// ---------------------------------------------------------------------------
// Aggregation (R0 verbatim, proven ~18 us): 16 nodes/block, 16 lanes/node x
// 8 B, fp32 accumulate, bf16 out. High TLP (800K threads).
// ---------------------------------------------------------------------------
__global__ __launch_bounds__(256) void agg_kernel(
    const unsigned* __restrict__ feat8,
    const int*      __restrict__ edges,
    unsigned short* __restrict__ aggb)
{
    const int node = blockIdx.x * 16 + (threadIdx.x >> 4);
    const int l    = threadIdx.x & 15;
    const int* e   = edges + node * DEG;

    float a[8] = {0.f, 0.f, 0.f, 0.f, 0.f, 0.f, 0.f, 0.f};
    #pragma unroll
    for (int d = 0; d < DEG; ++d) {
        const int idx = e[d];
        const uint2 pk = *(const uint2*)(feat8 + (size_t)idx * (DF / 4) + l * 2);
#if HW_FP8
        const f32x2 v0 = __builtin_amdgcn_cvt_pk_f32_fp8((int)pk.x, false);
        const f32x2 v1 = __builtin_amdgcn_cvt_pk_f32_fp8((int)pk.x, true);
        const f32x2 v2 = __builtin_amdgcn_cvt_pk_f32_fp8((int)pk.y, false);
        const f32x2 v3 = __builtin_amdgcn_cvt_pk_f32_fp8((int)pk.y, true);
        a[0] += v0[0]; a[1] += v0[1]; a[2] += v1[0]; a[3] += v1[1];
        a[4] += v2[0]; a[5] += v2[1]; a[6] += v3[0]; a[7] += v3[1];
#else
        #pragma unroll
        for (int j = 0; j < 4; ++j) a[j]     += dec1_fp8((pk.x >> (8 * j)) & 255);
        #pragma unroll
        for (int j = 0; j < 4; ++j) a[4 + j] += dec1_fp8((pk.y >> (8 * j)) & 255);
#endif
    }

    const float s = 1.0f / (float)DEG;
    u16x8 o;
    #pragma unroll
    for (int j = 0; j < 8; ++j) o[j] = f2bf(a[j] * s);
    *(u16x8*)(aggb + (size_t)node * DF + l * 8) = o;
}

// ---------------------------------------------------------------------------
// GEMM v7: v6 body + coalesced LDS-transpose epilogue.
//  BM=64, BN=256, 512 threads = 8 waves 2m x 4n (wave tile 32x64).
//  A-self (kc 0,1) staged inline from fp32 feat; A-agg (kc 2,3) from aggb.
//  Epilogue: acc -> per-wave LDS scratch (reusing Bsw, LDP=68 pad) -> float4
//  stores: each 16-lane group writes 256 B contiguous (vs 64 B fragments).
// ---------------------------------------------------------------------------
#define BM  64
#define BN  256
#define LDT 72
#define LDP 68   // fp32 scratch row pitch: 272 B (16B-aligned rows, 2-way banks)

__global__ __launch_bounds__(512) void gemm_kernel(
    const float*          __restrict__ feat,
    const unsigned short* __restrict__ aggb,
    const unsigned short* __restrict__ Wt,
    float*                __restrict__ out)
{
    __shared__ __align__(16) unsigned short Asw[BM * LDT];   //  9.2 KB
    __shared__ __align__(16) unsigned short Bsw[BN * LDT];   // 36.9 KB

    const int tid = threadIdx.x;
    const int m0  = blockIdx.x * BM;

    const int wave = tid >> 6, lane = tid & 63;
    const int quad = lane >> 4, lr = lane & 15;
    const int wm   = (wave & 1) * 32;
    const int wn   = (wave >> 1) * 64;

    f32x4 acc[2][4] = {};

    for (int kc = 0; kc < 4; ++kc) {
        if (kc) __syncthreads();

        // A chunk: 64 rows x 64 cols, 1 seg/thread
        {
            const int r = tid >> 3;
            const int c = (tid & 7) * 8;
            int node = m0 + r;
            if (node >= NN) node = NN - 1;
            if (kc < 2) {
                const float* src = feat + (size_t)node * DF + kc * 64 + c;
                const float4 v0 = *(const float4*)(src);
                const float4 v1 = *(const float4*)(src + 4);
                u16x8 o;
                o[0] = f2bf(v0.x); o[1] = f2bf(v0.y); o[2] = f2bf(v0.z); o[3] = f2bf(v0.w);
                o[4] = f2bf(v1.x); o[5] = f2bf(v1.y); o[6] = f2bf(v1.z); o[7] = f2bf(v1.w);
                *(u16x8*)(Asw + r * LDT + c) = o;
            } else {
                *(u16x8*)(Asw + r * LDT + c) =
                    *(const u16x8*)(aggb + (size_t)node * DF + (kc - 2) * 64 + c);
            }
        }

        // B chunk: 256 rows x 64 cols from Wt (L2-resident), 4 segs/thread
        #pragma unroll
        for (int it = 0; it < 4; ++it) {
            const int sidx = it * 512 + tid;
            const int r = sidx >> 3;
            const int c = (sidx & 7) * 8;
            *(u16x8*)(Bsw + r * LDT + c) =
                *(const u16x8*)(Wt + (size_t)r * DO + kc * 64 + c);
        }

        __syncthreads();

        #pragma unroll
        for (int kk = 0; kk < 64; kk += 32) {
            const int kb = kk + quad * 8;
            bf16x8 af[2], bfr[4];
            #pragma unroll
            for (int i = 0; i < 2; ++i)
                af[i] = *(const bf16x8*)(Asw + (wm + i * 16 + lr) * LDT + kb);
            #pragma unroll
            for (int i = 0; i < 4; ++i)
                bfr[i] = *(const bf16x8*)(Bsw + (wn + i * 16 + lr) * LDT + kb);
            #pragma unroll
            for (int mi = 0; mi < 2; ++mi)
                #pragma unroll
                for (int ni = 0; ni < 4; ++ni)
                    acc[mi][ni] = __builtin_amdgcn_mfma_f32_16x16x32_bf16(
                        af[mi], bfr[ni], acc[mi][ni], 0, 0, 0);
        }
    }

    // ---- epilogue: relu + LDS transpose -> coalesced float4 stores
    __syncthreads();                         // all MFMA LDS reads done
    float* ws = (float*)Bsw + wave * (16 * LDP);   // 4352 B per wave (34.8 KB)

    #pragma unroll
    for (int mi = 0; mi < 2; ++mi) {
        #pragma unroll
        for (int ni = 0; ni < 4; ++ni)
            #pragma unroll
            for (int r = 0; r < 4; ++r)
                ws[(quad * 4 + r) * LDP + ni * 16 + lr] =
                    fmaxf(acc[mi][ni][r], 0.f);

        __syncthreads();                     // writes visible (also WAR fence)

        #pragma unroll
        for (int p = 0; p < 4; ++p) {
            const int row = p * 4 + (lane >> 4);   // 0..15
            const int cg  = (lane & 15) * 4;       // 0..60
            const float4 v = *(const float4*)(ws + row * LDP + cg);
            const int grow = m0 + wm + mi * 16 + row;
            if (grow < NN)
                *(float4*)(out + (size_t)grow * DO + wn + cg) = v;
        }

        __syncthreads();                     // before mi=1 overwrites scratch
    }
}

extern "C" void kernel_launch(void* const* d_in, const int* in_sizes, int n_in,
                              void* d_out, int out_size, void* d_ws, size_t ws_size,
                              hipStream_t stream)
{
    const float* feat  = (const float*)d_in[0];
    const int*   edges = (const int*)d_in[1];
    const float* W     = (const float*)d_in[2];
    float*       out   = (float*)d_out;

    unsigned short* aggb  = (unsigned short*)d_ws;                 // 12.8 MB
    unsigned*       feat8 = (unsigned*)(aggb + (size_t)NN * DF);   // 6.4 MB
    unsigned short* Wt    = (unsigned short*)(feat8 + (size_t)NN * DF / 4); // 128 KB

    convert_kernel<<<(FEAT4 + DO * DO + 255) / 256, 256, 0, stream>>>(
        feat, W, feat8, Wt);
    agg_kernel<<<NN / 16, 256, 0, stream>>>(feat8, edges, aggb);

    gemm_kernel<<<(NN + BM - 1) / BM, 512, 0, stream>>>(feat, aggb, Wt, out);
}